// Round 7
// baseline (165.204 us; speedup 1.0000x reference)
//
#include <hip/hip_runtime.h>

// DeformConv fused: barrier-free main loop, fragment-tiled global B.
// B=4, C=128, H=W=96, O=128, 3x3 s1 p1 d1, G=1.
#define CIN   128
#define HH    96
#define WW    96
#define OUTC  128
#define HWSZ  9216
#define KK    9
#define KTOT  1152

typedef __bf16 bf16x8 __attribute__((ext_vector_type(8)));
typedef float  f32x4  __attribute__((ext_vector_type(4)));

__device__ __forceinline__ unsigned short f2bf(float f) {
  unsigned u = __builtin_bit_cast(unsigned, f);
  u += 0x7fffu + ((u >> 16) & 1u);               // RNE
  return (unsigned short)(u >> 16);
}
__device__ __forceinline__ float bf2f_lo(unsigned w) {
  unsigned u = w << 16;
  return __builtin_bit_cast(float, u);
}
__device__ __forceinline__ float bf2f_hi(unsigned w) {
  unsigned u = w & 0xffff0000u;
  return __builtin_bit_cast(float, u);
}
__device__ __forceinline__ unsigned pack_bf(float v0, float v1) {
  unsigned u0 = __builtin_bit_cast(unsigned, v0) + 0x8000u;
  unsigned u1 = __builtin_bit_cast(unsigned, v1) + 0x8000u;
  return __builtin_amdgcn_perm(u1, u0, 0x07060302u);
}

// ws layout (u16 offsets):
//   wtt   bf16 tiled [tap][ks][nt(8)][lane(64)][8]  @ 0       (147456)
//         lane = quad*16 + l15 ; o = nt*16+l15 ; c = ks*32+quad*8+j
//   wt2t  bf16 tiled [tap][ks][nt2(2)][lane(64)][8] @ 147456  (36864)
//   bias32 f32[32]                                  @ 184320  (64 u16)
//   xn    bf16[4][9216][128]  @ 184384   (NHWC)
//   x2n   bf16[4][9216][128]  @ 184384+4718592
#define WT2T_O 147456
#define BIAS_O 184320
#define XN_O   184384
#define X2N_O  (184384 + 4718592)

__global__ __launch_bounds__(256) void prep_all(
    const float* __restrict__ x, const float* __restrict__ x2,
    const float* __restrict__ offw, const float* __restrict__ maskw,
    const float* __restrict__ defw, const float* __restrict__ offb,
    const float* __restrict__ maskb, void* __restrict__ wsv) {
  int bid = blockIdx.x;
  int t = threadIdx.x;
  if (bid < 1152) {
    __shared__ unsigned short tile[64][138];
    int tsel = bid / 576;
    int rem = bid - tsel * 576;
    int b = rem / 144;
    int hw0 = (rem % 144) * 64;
    const float* src = tsel ? x2 : x;
    unsigned short* dst = (unsigned short*)wsv + (tsel ? X2N_O : XN_O);
    int px = t & 63, cg = t >> 6;
#pragma unroll
    for (int q = 0; q < 16; ++q) {
      int c = cg * 32 + 2 * q;
      float f0 = src[((size_t)(b * CIN + c))     * HWSZ + hw0 + px];
      float f1 = src[((size_t)(b * CIN + c + 1)) * HWSZ + hw0 + px];
      *(unsigned*)&tile[px][c] = pack_bf(f0, f1);
    }
    __syncthreads();
    unsigned* drow = (unsigned*)(dst + ((size_t)(b * HWSZ + hw0)) * 128);
#pragma unroll
    for (int k = 0; k < 16; ++k) {
      int e = t + 256 * k;
      int pxx = e >> 6, j = e & 63;
      unsigned v = *(const unsigned*)&tile[pxx][2 * j];
      drow[(size_t)pxx * 64 + j] = v;
    }
    return;
  }
  unsigned short* wtt  = (unsigned short*)wsv;
  unsigned short* wt2t = wtt + WT2T_O;
  float* bias32 = (float*)(wtt + BIAS_O);
  int idx = (bid - 1152) * 256 + t;
  if (idx < OUTC * KTOT) {
    int o = idx / KTOT, r = idx - o * KTOT;
    int c = r / KK, tap = r - c * KK;
    int nt = o >> 4, l15o = o & 15;
    int ks = c >> 5, quad = (c >> 3) & 3, j = c & 7;
    wtt[(size_t)(((tap * 4 + ks) * 8 + nt) * 64 + quad * 16 + l15o) * 8 + j] =
        f2bf(defw[idx]);
  } else if (idx < OUTC * KTOT + 32 * KTOT) {
    int jj = idx - OUTC * KTOT;
    int oc = jj / KTOT, r = jj - oc * KTOT;
    int c = r / KK, tap = r - c * KK;
    float v = 0.f;
    if (oc < 18)      v = offw[jj];
    else if (oc < 27) v = maskw[jj - 18 * KTOT];
    int nt2 = oc >> 4, l15o = oc & 15;
    int ks = c >> 5, quad = (c >> 3) & 3, j = c & 7;
    wt2t[(size_t)(((tap * 4 + ks) * 2 + nt2) * 64 + quad * 16 + l15o) * 8 + j] =
        f2bf(v);
  } else if (idx < OUTC * KTOT + 32 * KTOT + 32) {
    int j = idx - OUTC * KTOT - 32 * KTOT;
    float v = 0.f;
    if (j < 18) v = offb[j]; else if (j < 27) v = maskb[j - 18];
    bias32[j] = v;
  }
}

// Fused: block = 64-px strip; wave w = m-tile w (16 px) x all 128 o.
// A: row-coalesced gather -> wave-private LDS round-trip (stride 72 dw).
// B: fragment-tiled global loads (1KB lane-linear, L1/L2). No main-loop barriers.
__global__ __launch_bounds__(256, 3) void fused(
    const float* __restrict__ defb, const void* __restrict__ wsv,
    float* __restrict__ out) {
  const unsigned short* wtt  = (const unsigned short*)wsv;
  const unsigned short* wt2t = wtt + WT2T_O;
  const float* bias32 = (const float*)(wtt + BIAS_O);
  const unsigned short* xn  = wtt + XN_O;
  const unsigned short* x2n = wtt + X2N_O;

  __shared__ unsigned short val[64][144];  // 18.4 KB, stride 72 dw (4-way max)
  __shared__ float om[32][68];             // 8.7 KB
  __shared__ unsigned sidxw[KK * 4 * 64];  // 9.2 KB: idx | bf16wgt<<16

  int t = threadIdx.x;
  int w = t >> 6;
  int l = t & 63;
  int l15 = l & 15, quad = l >> 4;
  int rb = blockIdx.x;
  int bid = (rb & 7) * 72 + (rb >> 3);     // XCD swizzle
  int b = bid / 144;
  int pblk = (bid % 144) * 64;

  int phg[4], pwg[4];
#pragma unroll
  for (int G = 0; G < 4; ++G) {
    int p = pblk + w * 16 + G * 4 + quad;
    phg[G] = p / WW;
    pwg[G] = p - phg[G] * WW;
  }

  // ===== phase 1: offset/mask GEMM (barrier-free) =====
  f32x4 oa0 = {0.f, 0.f, 0.f, 0.f};
  f32x4 oa1 = {0.f, 0.f, 0.f, 0.f};
  const unsigned short* x2nb = x2n + ((size_t)b * HWSZ) * 128;
  for (int tap = 0; tap < KK; ++tap) {
    int ky = tap / 3 - 1, kx = tap % 3 - 1;
#pragma unroll
    for (int G = 0; G < 4; ++G) {
      int y = phg[G] + ky, xx = pwg[G] + kx;
      bool ok = ((unsigned)y < HH) && ((unsigned)xx < WW);
      int pos = ok ? (y * WW + xx) : 0;
      uint4 v = *(const uint4*)(x2nb + ((size_t)pos << 7) + l15 * 8);
      if (!ok) v = make_uint4(0u, 0u, 0u, 0u);
      *(uint4*)&val[w * 16 + G * 4 + quad][l15 * 8] = v;
    }
#pragma unroll
    for (int ks = 0; ks < 4; ++ks) {
      bf16x8 af = *(const bf16x8*)&val[w * 16 + l15][ks * 32 + quad * 8];
      const unsigned short* bp = wt2t + (size_t)(((tap * 4 + ks) * 2) * 64 + l) * 8;
      bf16x8 b0 = *(const bf16x8*)bp;
      bf16x8 b1 = *(const bf16x8*)(bp + 64 * 8);
      oa0 = __builtin_amdgcn_mfma_f32_16x16x32_bf16(af, b0, oa0, 0, 0, 0);
      oa1 = __builtin_amdgcn_mfma_f32_16x16x32_bf16(af, b1, oa1, 0, 0, 0);
    }
  }
#pragma unroll
  for (int nt = 0; nt < 2; ++nt) {
    f32x4 a = nt ? oa1 : oa0;
    int oc = nt * 16 + l15;
    float bia = bias32[oc];
#pragma unroll
    for (int r = 0; r < 4; ++r)
      om[oc][w * 16 + quad * 4 + r] = a[r] + bia;
  }
  __syncthreads();

  // ===== phase 2: bilinear params -> sidxw =====
  for (int e = t; e < KK * 64; e += 256) {
    int tap = e >> 6, pp = e & 63;
    int gp2 = pblk + pp;
    int h = gp2 / WW, ww_ = gp2 % WW;
    float dy = om[2 * tap][pp], dx = om[2 * tap + 1][pp];
    float mr = om[18 + tap][pp];
    float m = 1.f / (1.f + __expf(-mr));
    float py  = (float)(h + tap / 3 - 1) + dy;
    float pxx = (float)(ww_ + tap % 3 - 1) + dx;
    float y0f = floorf(py), x0f = floorf(pxx);
    int y0 = (int)y0f, x0 = (int)x0f;
    float ly = py - y0f, lx = pxx - x0f;
    int y1 = y0 + 1, x1 = x0 + 1;
    bool vy0 = (unsigned)y0 < HH, vy1 = (unsigned)y1 < HH;
    bool vx0 = (unsigned)x0 < WW, vx1 = (unsigned)x1 < WW;
    int cy0 = min(max(y0, 0), HH - 1), cy1 = min(max(y1, 0), HH - 1);
    int cx0 = min(max(x0, 0), WW - 1), cx1 = min(max(x1, 0), WW - 1);
    unsigned i00 = cy0 * WW + cx0, i01 = cy0 * WW + cx1;
    unsigned i10 = cy1 * WW + cx0, i11 = cy1 * WW + cx1;
    float w00 = (vy0 && vx0) ? m * (1.f - ly) * (1.f - lx) : 0.f;
    float w01 = (vy0 && vx1) ? m * (1.f - ly) * lx         : 0.f;
    float w10 = (vy1 && vx0) ? m * ly * (1.f - lx)         : 0.f;
    float w11 = (vy1 && vx1) ? m * ly * lx                 : 0.f;
    sidxw[(tap * 4 + 0) * 64 + pp] = i00 | ((unsigned)f2bf(w00) << 16);
    sidxw[(tap * 4 + 1) * 64 + pp] = i01 | ((unsigned)f2bf(w01) << 16);
    sidxw[(tap * 4 + 2) * 64 + pp] = i10 | ((unsigned)f2bf(w10) << 16);
    sidxw[(tap * 4 + 3) * 64 + pp] = i11 | ((unsigned)f2bf(w11) << 16);
  }
  __syncthreads();

  // ===== phase 3: deformable GEMM (barrier-free) =====
  f32x4 acc[8];
#pragma unroll
  for (int nt = 0; nt < 8; ++nt) acc[nt] = (f32x4){0.f, 0.f, 0.f, 0.f};
  const unsigned short* xnb = xn + ((size_t)b * HWSZ) * 128;

  for (int tap = 0; tap < KK; ++tap) {
    unsigned sw[4][4];
#pragma unroll
    for (int cr = 0; cr < 4; ++cr)
#pragma unroll
      for (int G = 0; G < 4; ++G)
        sw[cr][G] = sidxw[(tap * 4 + cr) * 64 + w * 16 + G * 4 + quad];
    uint4 v[4][4];
#pragma unroll
    for (int G = 0; G < 4; ++G)
#pragma unroll
      for (int cr = 0; cr < 4; ++cr)
        v[cr][G] = *(const uint4*)(xnb + ((size_t)(sw[cr][G] & 0xffffu) << 7) + l15 * 8);
#pragma unroll
    for (int G = 0; G < 4; ++G) {
      float f[8];
#pragma unroll
      for (int j = 0; j < 8; ++j) f[j] = 0.f;
#pragma unroll
      for (int cr = 0; cr < 4; ++cr) {
        float wc = bf2f_hi(sw[cr][G]);
        const unsigned* a = (const unsigned*)&v[cr][G];
#pragma unroll
        for (int j = 0; j < 4; ++j) {
          f[2 * j]     += wc * bf2f_lo(a[j]);
          f[2 * j + 1] += wc * bf2f_hi(a[j]);
        }
      }
      unsigned od[4];
#pragma unroll
      for (int j = 0; j < 4; ++j) od[j] = pack_bf(f[2 * j], f[2 * j + 1]);
      *(uint4*)&val[w * 16 + G * 4 + quad][l15 * 8] =
          make_uint4(od[0], od[1], od[2], od[3]);
    }
    bf16x8 af[4];
#pragma unroll
    for (int ks = 0; ks < 4; ++ks)
      af[ks] = *(const bf16x8*)&val[w * 16 + l15][ks * 32 + quad * 8];
#pragma unroll
    for (int ks = 0; ks < 4; ++ks) {
      const unsigned short* bp = wtt + (size_t)(((tap * 4 + ks) * 8) * 64 + l) * 8;
#pragma unroll
      for (int nt = 0; nt < 8; ++nt) {
        bf16x8 bb = *(const bf16x8*)(bp + (size_t)nt * 64 * 8);
        acc[nt] = __builtin_amdgcn_mfma_f32_16x16x32_bf16(af[ks], bb, acc[nt], 0, 0, 0);
      }
    }
  }

  // ===== phase 4: epilogue =====
  for (int r = 0; r < 4; ++r) {
    f32x4 a0 = acc[2 * r], a1 = acc[2 * r + 1];
    float db0 = defb[r * 32 + l15];
    float db1 = defb[r * 32 + 16 + l15];
    if (r) __syncthreads();
#pragma unroll
    for (int reg = 0; reg < 4; ++reg) {
      om[l15]     [w * 16 + quad * 4 + reg] = a0[reg] + db0;
      om[16 + l15][w * 16 + quad * 4 + reg] = a1[reg] + db1;
    }
    __syncthreads();
    int row = t >> 4;
    int col4 = (t & 15) * 4;
#pragma unroll
    for (int hrow = 0; hrow < 2; ++hrow) {
      int rr = row + hrow * 16;
      float4 vv = *(float4*)&om[rr][col4];
      *(float4*)&out[((size_t)b * OUTC + r * 32 + rr) * HWSZ + pblk + col4] = vv;
    }
  }
}

extern "C" void kernel_launch(void* const* d_in, const int* in_sizes, int n_in,
                              void* d_out, int out_size, void* d_ws, size_t ws_size,
                              hipStream_t stream) {
  const float* x     = (const float*)d_in[0];
  const float* x2    = (const float*)d_in[1];
  const float* offw  = (const float*)d_in[2];
  const float* offb  = (const float*)d_in[3];
  const float* maskw = (const float*)d_in[4];
  const float* maskb = (const float*)d_in[5];
  const float* defw  = (const float*)d_in[6];
  const float* defb  = (const float*)d_in[7];
  float* out = (float*)d_out;

  hipLaunchKernelGGL(prep_all, dim3(1873), dim3(256), 0, stream,
                     x, x2, offw, maskw, defw, offb, maskb, d_ws);
  hipLaunchKernelGGL(fused, dim3(576), dim3(256), 0, stream, defb, d_ws, out);
}